// Round 7
// baseline (605.959 us; speedup 1.0000x reference)
//
#include <hip/hip_runtime.h>
#include <hip/hip_bf16.h>

// NonLocalBlock2D: x[8,256,64,64] fp32
// All-fp16 pipeline (f logits stored fp16, stats fp32), batches in PAIRS:
//   k_prep_w  : weights -> wAll fp16 [384][256], Wc fp16 [256][128]
//   k_split_x : transpose x -> xT fp16 [b][n][c]
//   k_proj    : fp16 GEMM 64x64/wave -> th/ph fp16 [b][n][c], gT fp16 [b][c][n]
//   k_gemm1   : f fp16 = theta·phi; epilogue lmax/lsum per (64-row-block, col)
//               computed from the fp16-ROUNDED logits (consistent with gemm2)
//   k_prep    : cmax[m], crcp[m]; gs[c][m] = fp16(g[c][m]*crcp[m])
//   k_gemm2   : wave = 16n x 128c x 512m-chunk; reads f ONCE, exps ONCE,
//               P on the fly -> fp16 MFMA vs gs -> partial[kc]
//   k_reduce  : yT[b][n][c] fp16 = sum_kc partial
//   k_conv    : out = Wc·yT + Wb + x

#define IC   128
#define CIN  256
#define NPOS 4096
#define NB   8

typedef _Float16 f16;
typedef __attribute__((ext_vector_type(8))) _Float16 f16x8;
typedef __attribute__((ext_vector_type(4))) _Float16 f16x4;
typedef __attribute__((ext_vector_type(4))) float f32x4;
typedef __attribute__((ext_vector_type(4))) float fvec4;

#define MFMA16(a, b, c) __builtin_amdgcn_mfma_f32_16x16x32_f16((a), (b), (c), 0, 0, 0)

// ---------------- weight prep: wAll fp16 [384][256], Wc fp16 [256][128] ----------------
__global__ __launch_bounds__(256) void k_prep_w(
    const float* __restrict__ gw, const float* __restrict__ tw, const float* __restrict__ pw,
    const float* __restrict__ Ww, f16* __restrict__ wAll, f16* __restrict__ Wc)
{
    const int idx = (blockIdx.x * 256 + threadIdx.x) * 4;
    if (idx < 384 * 256) {
        const int row = idx >> 8, col = idx & 255;
        const float* src = (row < 128) ? (gw + row * 256)
                         : (row < 256) ? (tw + (row - 128) * 256)
                                       : (pw + (row - 256) * 256);
        fvec4 v = *reinterpret_cast<const fvec4*>(src + col);
        f16x4 o = { (f16)v[0], (f16)v[1], (f16)v[2], (f16)v[3] };
        *reinterpret_cast<f16x4*>(wAll + idx) = o;
    } else {
        const int j = idx - 384 * 256;          // over 256*128
        fvec4 v = *reinterpret_cast<const fvec4*>(Ww + j);
        f16x4 o = { (f16)v[0], (f16)v[1], (f16)v[2], (f16)v[3] };
        *reinterpret_cast<f16x4*>(Wc + j) = o;
    }
}

// ---------------- transpose x: [b][c][n] fp32 -> [b][n][c] fp16 ----------------
__global__ __launch_bounds__(256) void k_split_x(
    const float* __restrict__ x, f16* __restrict__ xT)
{
    __shared__ float tile[64][65];
    const int b  = blockIdx.z;
    const int c0 = blockIdx.y * 64;
    const int n0 = blockIdx.x * 64;
    const int t  = threadIdx.x;
    {
        const int cc = t >> 4, nn = (t & 15) * 4;
        const float* src = x + ((size_t)b * CIN + c0) * NPOS + n0;
#pragma unroll
        for (int p = 0; p < 4; ++p) {
            fvec4 v = *reinterpret_cast<const fvec4*>(src + (size_t)(cc + p * 16) * NPOS + nn);
            tile[cc + p * 16][nn + 0] = v[0];
            tile[cc + p * 16][nn + 1] = v[1];
            tile[cc + p * 16][nn + 2] = v[2];
            tile[cc + p * 16][nn + 3] = v[3];
        }
    }
    __syncthreads();
    {
        const int c4 = (t & 15) * 4, nr = t >> 4;
#pragma unroll
        for (int p = 0; p < 4; ++p) {
            const int n = nr + p * 16;
            f16x4 o = { (f16)tile[c4 + 0][n], (f16)tile[c4 + 1][n],
                        (f16)tile[c4 + 2][n], (f16)tile[c4 + 3][n] };
            *reinterpret_cast<f16x4*>(xT + ((size_t)b * NPOS + n0 + n) * CIN + c0 + c4) = o;
        }
    }
}

// ---------------- projections: fp16 GEMM, 64x64 per wave ----------------
__global__ __launch_bounds__(256) void k_proj(
    const f16* __restrict__ xT, const f16* __restrict__ wAll,
    const float* __restrict__ gb, const float* __restrict__ tb, const float* __restrict__ pb,
    f16* __restrict__ th, f16* __restrict__ ph, f16* __restrict__ gT)
{
    const int w    = threadIdx.x >> 6;
    const int lane = threadIdx.x & 63;
    const int lrow = lane & 15;
    const int kg   = lane >> 4;
    const int b    = blockIdx.z;
    const int c0   = blockIdx.y * 64;              // [0,384)
    const int n0   = blockIdx.x * 256 + w * 64;

    const f16* X = xT + (size_t)b * NPOS * CIN;

    f32x4 acc[4][4] = {};
#pragma unroll
    for (int ks = 0; ks < 8; ++ks) {
        const int k = ks * 32 + kg * 8;
        f16x8 a[4], bv[4];
#pragma unroll
        for (int i = 0; i < 4; ++i) {
            a[i]  = *reinterpret_cast<const f16x8*>(wAll + (size_t)(c0 + i * 16 + lrow) * CIN + k);
            bv[i] = *reinterpret_cast<const f16x8*>(X + (size_t)(n0 + i * 16 + lrow) * CIN + k);
        }
#pragma unroll
        for (int i = 0; i < 4; ++i)
#pragma unroll
            for (int j = 0; j < 4; ++j)
                acc[i][j] = MFMA16(a[i], bv[j], acc[i][j]);
    }
    const int set = c0 >> 7;                 // 0:g 1:theta 2:phi
    if (set == 0) {
#pragma unroll
        for (int i = 0; i < 4; ++i) {
            const int c = c0 + i * 16 + kg * 4;
#pragma unroll
            for (int j = 0; j < 4; ++j) {
                const int n = n0 + j * 16 + lrow;
#pragma unroll
                for (int r = 0; r < 4; ++r)
                    gT[((size_t)b * IC + c + r) * NPOS + n] = (f16)(acc[i][j][r] + gb[c + r]);
            }
        }
    } else {
        const float* Bi = (set == 1) ? tb : pb;
        f16* dst = (set == 1) ? th : ph;
        const int cl0 = (c0 & 127);
#pragma unroll
        for (int i = 0; i < 4; ++i) {
            const int c = cl0 + i * 16 + kg * 4;
#pragma unroll
            for (int j = 0; j < 4; ++j) {
                const int n = n0 + j * 16 + lrow;
                f16x4 o = { (f16)(acc[i][j][0] + Bi[c + 0]), (f16)(acc[i][j][1] + Bi[c + 1]),
                            (f16)(acc[i][j][2] + Bi[c + 2]), (f16)(acc[i][j][3] + Bi[c + 3]) };
                *reinterpret_cast<f16x4*>(dst + ((size_t)b * NPOS + n) * IC + c) = o;
            }
        }
    }
}

// ---- GEMM1 (pair): f[bi][n][m] = fp16(theta[n]·phi[m]); epilogue lmax/lsum ----
__global__ __launch_bounds__(256) void k_gemm1(
    const f16* __restrict__ th, const f16* __restrict__ ph,
    f16* __restrict__ f, float* __restrict__ lmax, float* __restrict__ lsum, int b0)
{
    const int w    = threadIdx.x >> 6;
    const int lane = threadIdx.x & 63;
    const int lrow = lane & 15;
    const int kg   = lane >> 4;
    const int gwid = blockIdx.x * 4 + w;      // 0..8191
    const int bi   = gwid >> 12;
    const int tid  = gwid & 4095;
    const int n0   = (tid >> 6) * 64;
    const int m0   = (tid & 63) * 64;

    const f16* A = th + (size_t)(b0 + bi) * NPOS * IC;
    const f16* B = ph + (size_t)(b0 + bi) * NPOS * IC;
    f16* fb = f + (size_t)bi * NPOS * NPOS;

    f32x4 acc[4][4] = {};
#pragma unroll
    for (int ks = 0; ks < 4; ++ks) {
        const int k = ks * 32 + kg * 8;
        f16x8 a[4], bv[4];
#pragma unroll
        for (int i = 0; i < 4; ++i) {
            a[i]  = *reinterpret_cast<const f16x8*>(A + (size_t)(n0 + i * 16 + lrow) * IC + k);
            bv[i] = *reinterpret_cast<const f16x8*>(B + (size_t)(m0 + i * 16 + lrow) * IC + k);
        }
#pragma unroll
        for (int i = 0; i < 4; ++i)
#pragma unroll
            for (int j = 0; j < 4; ++j)
                acc[i][j] = MFMA16(a[i], bv[j], acc[i][j]);
    }
    // store fp16 logits; replace acc with the rounded value for consistent stats
#pragma unroll
    for (int i = 0; i < 4; ++i)
#pragma unroll
        for (int j = 0; j < 4; ++j)
#pragma unroll
            for (int r = 0; r < 4; ++r) {
                f16 h = (f16)acc[i][j][r];
                fb[(size_t)(n0 + i * 16 + kg * 4 + r) * NPOS + m0 + j * 16 + lrow] = h;
                acc[i][j][r] = (float)h;
            }

    // per-column (64 rows of this wave) max and exp-sum; deterministic, no atomics
    const int rowblk = n0 >> 6;
#pragma unroll
    for (int j = 0; j < 4; ++j) {
        float cm = -3.0e38f;
#pragma unroll
        for (int i = 0; i < 4; ++i)
#pragma unroll
            for (int r = 0; r < 4; ++r)
                cm = fmaxf(cm, acc[i][j][r]);
        cm = fmaxf(cm, __shfl_xor(cm, 16));
        cm = fmaxf(cm, __shfl_xor(cm, 32));
        float s = 0.f;
#pragma unroll
        for (int i = 0; i < 4; ++i)
#pragma unroll
            for (int r = 0; r < 4; ++r)
                s += __expf(acc[i][j][r] - cm);
        s += __shfl_xor(s, 16);
        s += __shfl_xor(s, 32);
        if (kg == 0) {
            const size_t off = ((size_t)bi * 64 + rowblk) * NPOS + m0 + j * 16 + lrow;
            lmax[off] = cm;
            lsum[off] = s;
        }
    }
}

// ---- prep (pair): cmax/crcp from lmax/lsum; gs[c][m] = fp16(g[c][m]*crcp[m]) ----
__global__ __launch_bounds__(256) void k_prep(
    const float* __restrict__ lmax, const float* __restrict__ lsum,
    const f16* __restrict__ gT, float* __restrict__ cmaxp, f16* __restrict__ gs, int b0)
{
    const int bi = blockIdx.z;
    const int m  = blockIdx.x * 256 + threadIdx.x;
    const float* lm = lmax + (size_t)bi * 64 * NPOS;
    const float* ls = lsum + (size_t)bi * 64 * NPOS;
    float cm = -3.0e38f;
#pragma unroll 8
    for (int rb = 0; rb < 64; ++rb)
        cm = fmaxf(cm, lm[(size_t)rb * NPOS + m]);
    float s = 0.f;
#pragma unroll 8
    for (int rb = 0; rb < 64; ++rb)
        s += __expf(lm[(size_t)rb * NPOS + m] - cm) * ls[(size_t)rb * NPOS + m];
    const float rc = 1.0f / s;
    if (blockIdx.y == 0)
        cmaxp[(size_t)bi * NPOS + m] = cm;
    const f16* gb = gT + (size_t)(b0 + bi) * IC * NPOS;
    f16* gsb = gs + (size_t)bi * IC * NPOS;
    const int cb = blockIdx.y * 16;
#pragma unroll
    for (int j = 0; j < 16; ++j) {
        const int c = cb + j;
        gsb[(size_t)c * NPOS + m] = (f16)((float)gb[(size_t)c * NPOS + m] * rc);
    }
}

// ---- GEMM2 (pair): wave = 16n x 128c x 512m-chunk; f read once, exp once ----
__global__ __launch_bounds__(256) void k_gemm2(
    const f16* __restrict__ f, const float* __restrict__ cmaxp,
    const f16* __restrict__ gs, float* __restrict__ partial)
{
    const int w    = threadIdx.x >> 6;
    const int lane = threadIdx.x & 63;
    const int lrow = lane & 15;
    const int kg   = lane >> 4;
    const int gwid = blockIdx.x * 4 + w;      // 0..4095
    const int bi   = gwid >> 11;
    const int rest = gwid & 2047;
    const int kc   = rest & 7;                // m-chunk of 512
    const int nb   = rest >> 3;               // 0..255, n-block of 16
    const int n0   = nb * 16;

    const f16* fb    = f + (size_t)bi * NPOS * NPOS;
    const float* cmb = cmaxp + (size_t)bi * NPOS;
    const f16* gsb   = gs + (size_t)bi * IC * NPOS;
    const f16* frow  = fb + (size_t)(n0 + lrow) * NPOS;

    f32x4 acc[8] = {};
#pragma unroll 2
    for (int ks = 0; ks < 16; ++ks) {
        const int k = kc * 512 + ks * 32 + kg * 8;
        f16x8 lv = *reinterpret_cast<const f16x8*>(frow + k);
        fvec4 cm0 = *reinterpret_cast<const fvec4*>(cmb + k);
        fvec4 cm1 = *reinterpret_cast<const fvec4*>(cmb + k + 4);
        f16x8 e;
        e[0] = (f16)__expf((float)lv[0] - cm0[0]);
        e[1] = (f16)__expf((float)lv[1] - cm0[1]);
        e[2] = (f16)__expf((float)lv[2] - cm0[2]);
        e[3] = (f16)__expf((float)lv[3] - cm0[3]);
        e[4] = (f16)__expf((float)lv[4] - cm1[0]);
        e[5] = (f16)__expf((float)lv[5] - cm1[1]);
        e[6] = (f16)__expf((float)lv[6] - cm1[2]);
        e[7] = (f16)__expf((float)lv[7] - cm1[3]);
#pragma unroll
        for (int i = 0; i < 8; ++i) {
            f16x8 a = *reinterpret_cast<const f16x8*>(gsb + (size_t)(i * 16 + lrow) * NPOS + k);
            acc[i] = MFMA16(a, e, acc[i]);
        }
    }
    float* pb = partial + ((size_t)bi * 8 + kc) * NPOS * IC;
    const int n = n0 + lrow;
#pragma unroll
    for (int i = 0; i < 8; ++i)
        *reinterpret_cast<fvec4*>(pb + (size_t)n * IC + i * 16 + kg * 4) = acc[i];
}

// ---------------- reduce partials (pair) -> yT[b][n][c] fp16 ----------------
__global__ __launch_bounds__(256) void k_reduce(
    const float* __restrict__ partial, f16* __restrict__ yT, int b0)
{
    const int bi  = blockIdx.y;
    const int idx = blockIdx.x * 256 + threadIdx.x;   // over NPOS*IC/4
    const fvec4* p = reinterpret_cast<const fvec4*>(partial + (size_t)bi * 8 * NPOS * IC);
    fvec4 s = p[idx];
#pragma unroll
    for (int kc = 1; kc < 8; ++kc) {
        fvec4 v = p[(size_t)kc * (NPOS * IC / 4) + idx];
        s[0] += v[0]; s[1] += v[1]; s[2] += v[2]; s[3] += v[3];
    }
    f16x4 o = { (f16)s[0], (f16)s[1], (f16)s[2], (f16)s[3] };
    *reinterpret_cast<f16x4*>(yT + (size_t)(b0 + bi) * NPOS * IC + (size_t)idx * 4) = o;
}

// ---------------- final conv + residual: 64x64 per wave ----------------
__global__ __launch_bounds__(256) void k_conv(
    const float* __restrict__ x, const f16* __restrict__ Wc, const float* __restrict__ Wb,
    const f16* __restrict__ yT, float* __restrict__ out)
{
    const int w    = threadIdx.x >> 6;
    const int lane = threadIdx.x & 63;
    const int lrow = lane & 15;
    const int kg   = lane >> 4;
    const int gwid = blockIdx.x * 4 + w;      // 0..2047
    const int ob   = gwid & 3;                // o-block of 64
    const int nb   = (gwid >> 2) & 63;        // n-block of 64
    const int b    = gwid >> 8;
    const int o0   = ob * 64;
    const int n0   = nb * 64;

    const f16* Y = yT + (size_t)b * NPOS * IC;
    f32x4 acc[4][4] = {};
#pragma unroll
    for (int ks = 0; ks < 4; ++ks) {
        const int k = ks * 32 + kg * 8;
        f16x8 a[4], bv[4];
#pragma unroll
        for (int i = 0; i < 4; ++i) {
            a[i]  = *reinterpret_cast<const f16x8*>(Wc + (size_t)(o0 + i * 16 + lrow) * IC + k);
            bv[i] = *reinterpret_cast<const f16x8*>(Y + (size_t)(n0 + i * 16 + lrow) * IC + k);
        }
#pragma unroll
        for (int i = 0; i < 4; ++i)
#pragma unroll
            for (int j = 0; j < 4; ++j)
                acc[i][j] = MFMA16(a[i], bv[j], acc[i][j]);
    }
#pragma unroll
    for (int i = 0; i < 4; ++i) {
        const int o = o0 + i * 16 + kg * 4;
#pragma unroll
        for (int j = 0; j < 4; ++j) {
            const int n = n0 + j * 16 + lrow;
#pragma unroll
            for (int r = 0; r < 4; ++r) {
                const size_t off = ((size_t)b * CIN + o + r) * NPOS + n;
                out[off] = acc[i][j][r] + x[off] + Wb[o + r];
            }
        }
    }
}

extern "C" void kernel_launch(void* const* d_in, const int* in_sizes, int n_in,
                              void* d_out, int out_size, void* d_ws, size_t ws_size,
                              hipStream_t stream)
{
    const float* x  = (const float*)d_in[0];
    const float* gw = (const float*)d_in[1];
    const float* gb = (const float*)d_in[2];
    const float* tw = (const float*)d_in[3];
    const float* tb = (const float*)d_in[4];
    const float* pw = (const float*)d_in[5];
    const float* pb = (const float*)d_in[6];
    const float* Ww = (const float*)d_in[7];
    const float* Wb = (const float*)d_in[8];
    float* out = (float*)d_out;

    char* ws = (char*)d_ws;
    size_t off = 0;
    auto alloc = [&](size_t bytes) -> char* {
        char* p = ws + off;
        off += (bytes + 255) & ~(size_t)255;
        return p;
    };
    f16* xT   = (f16*)alloc((size_t)NB * NPOS * CIN * 2);        // 16.8 MB
    f16* wAll = (f16*)alloc((size_t)384 * 256 * 2);
    f16* Wc   = (f16*)alloc((size_t)CIN * IC * 2);
    f16* th   = (f16*)alloc((size_t)NB * NPOS * IC * 2);         // 8.4 MB
    f16* ph   = (f16*)alloc((size_t)NB * NPOS * IC * 2);
    f16* gT   = (f16*)alloc((size_t)NB * NPOS * IC * 2);
    f16* f    = (f16*)alloc((size_t)2 * NPOS * NPOS * 2);        // 67 MB (pair)
    float* lmax = (float*)alloc((size_t)2 * 64 * NPOS * 4);      // 2.1 MB
    float* lsum = (float*)alloc((size_t)2 * 64 * NPOS * 4);
    float* cmaxp = (float*)alloc((size_t)2 * NPOS * 4);
    f16* gs   = (f16*)alloc((size_t)2 * IC * NPOS * 2);          // 2.1 MB
    float* partial = (float*)alloc((size_t)2 * 8 * NPOS * IC * 4); // 33.6 MB (pair)
    f16* yT   = (f16*)alloc((size_t)NB * NPOS * IC * 2);         // 8.4 MB

    k_prep_w<<<128, 256, 0, stream>>>(gw, tw, pw, Ww, wAll, Wc);
    k_split_x<<<dim3(64, 4, 8), 256, 0, stream>>>(x, xT);
    k_proj<<<dim3(16, 6, 8), 256, 0, stream>>>(xT, wAll, gb, tb, pb, th, ph, gT);

    for (int b0 = 0; b0 < NB; b0 += 2) {
        k_gemm1<<<2048, 256, 0, stream>>>(th, ph, f, lmax, lsum, b0);
        k_prep<<<dim3(16, 8, 2), 256, 0, stream>>>(lmax, lsum, gT, cmaxp, gs, b0);
        k_gemm2<<<1024, 256, 0, stream>>>(f, cmaxp, gs, partial);
        k_reduce<<<dim3(512, 2), 256, 0, stream>>>(partial, yT, b0);
    }
    k_conv<<<dim3(512), 256, 0, stream>>>(x, Wc, Wb, yT, out);
}